// Round 1
// baseline (584.616 us; speedup 1.0000x reference)
//
#include <hip/hip_runtime.h>

// ---------------------------------------------------------------------------
// ATFA: dual-axis conv-attention, MI355X fp16-MFMA implementation.
// Pipeline: prep(wT, xpad/fused) -> conv_qkv (implicit GEMM, N=1536)
//           -> attn_f (heads=(b,f), L=249) -> attn_t (heads=(b,t), L=64)
//           -> conv_final (K=9*768 -> 64), f32 out.
// ---------------------------------------------------------------------------

typedef _Float16 f16;
typedef _Float16 f16x8 __attribute__((ext_vector_type(8)));
typedef float    f32x4 __attribute__((ext_vector_type(4)));

#define B_   2
#define T_   249
#define F_   64
#define TP   251     // T + 2 (padded)
#define FP   66      // F + 2 (padded)
#define PIXB (T_*F_) // 15936 pixels per batch
#define NPIX (B_*PIXB)
#define LPAD 256     // padded attention length for the T-axis heads

static constexpr size_t FUSED_BYTES = (size_t)B_*TP*FP*768*2;  // 50,890,752
static constexpr size_t XPAD_BYTES  = (size_t)B_*TP*FP*256*2;  // 16,963,584
static constexpr size_t QF_BYTES    = (size_t)B_*64*LPAD*256*2;// 16,777,216
static constexpr size_t QT_BYTES    = (size_t)B_*T_*64*256*2;  // 16,318,464
static constexpr size_t WT_BYTES    = (size_t)9*1536*256*2;    //  7,077,888
static constexpr size_t WFT_BYTES   = (size_t)9*64*768*2;      //    884,736

static constexpr size_t OFF_FUSED = 0;
static constexpr size_t OFF_XPAD  = OFF_FUSED + FUSED_BYTES;
static constexpr size_t OFF_QF    = OFF_XPAD  + XPAD_BYTES;
static constexpr size_t OFF_KF    = OFF_QF + QF_BYTES;
static constexpr size_t OFF_VF    = OFF_KF + QF_BYTES;
static constexpr size_t OFF_QT    = OFF_VF + QF_BYTES;
static constexpr size_t OFF_KT    = OFF_QT + QT_BYTES;
static constexpr size_t OFF_VT    = OFF_KT + QT_BYTES;
static constexpr size_t OFF_WT    = OFF_VT + QT_BYTES;
static constexpr size_t OFF_WFT   = OFF_WT + WT_BYTES;
static constexpr size_t OFF_BALL  = OFF_WFT + WFT_BYTES;
static constexpr size_t OFF_BF    = OFF_BALL + 1536*4;
static constexpr size_t WS_NEED   = OFF_BF + 64*4;   // ~167 MiB

__device__ __forceinline__ f32x4 mfma16(f16x8 a, f16x8 b, f32x4 c) {
    return __builtin_amdgcn_mfma_f32_16x16x32_f16(a, b, c, 0, 0, 0);
}

// global -> LDS direct copy, 16B per lane. LDS dest must be wave-uniform
// (HW adds lane*16); global src is per-lane. CK-style integer casts.
__device__ __forceinline__ void gl_lds16(const void* g, void* l) {
    __builtin_amdgcn_global_load_lds(
        (const __attribute__((address_space(1))) unsigned int*)(unsigned long long)g,
        (__attribute__((address_space(3))) unsigned int*)(unsigned int)(unsigned long long)l,
        16, 0, 0);
}

// ---------------------------------------------------------------------------
// prep_w: pack all six QKV conv weights into wT[tap][n(1536)][c(256)] fp16
// (B^T layout for MFMA), swapping the 3x3 tap indices for the _f (AFAB)
// weights (conv on transposed image == conv with transposed taps).
// Also w_final -> wfT[tap][oc(64)][cin(768)], and pack biases.
// ---------------------------------------------------------------------------
__global__ __launch_bounds__(256) void prep_w(
    const float* __restrict__ wqf, const float* __restrict__ wkf, const float* __restrict__ wvf,
    const float* __restrict__ wqt, const float* __restrict__ wkt, const float* __restrict__ wvt,
    const float* __restrict__ wfin,
    const float* __restrict__ bqf, const float* __restrict__ bkf, const float* __restrict__ bvf,
    const float* __restrict__ bqt, const float* __restrict__ bkt, const float* __restrict__ bvt,
    const float* __restrict__ bfin,
    f16* __restrict__ wT, f16* __restrict__ wfT,
    float* __restrict__ biasAll, float* __restrict__ biasF)
{
    int idx = blockIdx.x*256 + threadIdx.x;
    if (idx < 9*1536*256) {
        int tap = idx / (1536*256);
        int r   = idx - tap*(1536*256);
        int n = r >> 8, c = r & 255;
        int dt = tap/3 - 1, df = tap%3 - 1;
        int blk = n >> 8, nl = n & 255;
        const float* w; int kh, kw;
        if (blk < 3) { w = (blk==0) ? wqf : (blk==1) ? wkf : wvf; kh = df+1; kw = dt+1; }
        else         { w = (blk==3) ? wqt : (blk==4) ? wkt : wvt; kh = dt+1; kw = df+1; }
        wT[idx] = (f16)w[((kh*3 + kw)*256 + c)*256 + nl];
    }
    if (idx < 9*64*768) {
        int tap = idx / (64*768);
        int r   = idx - tap*(64*768);
        int oc = r / 768, cin = r - oc*768;
        int dt = tap/3 - 1, df = tap%3 - 1;
        wfT[idx] = (f16)wfin[(((dt+1)*3 + (df+1))*768 + cin)*64 + oc];
    }
    if (idx < 1536) {
        int blk = idx >> 8, nl = idx & 255;
        const float* bb = (blk==0)?bqf:(blk==1)?bkf:(blk==2)?bvf:(blk==3)?bqt:(blk==4)?bkt:bvt;
        biasAll[idx] = bb[nl];
    }
    if (idx < 64) biasF[idx] = bfin[idx];
}

// ---------------------------------------------------------------------------
// prep_x: x (f32) -> xpad (padded fp16, zero borders via prior memset) and
// into fused[...][512..767] (the concat x-part).
// ---------------------------------------------------------------------------
__global__ __launch_bounds__(256) void prep_x(
    const float* __restrict__ x, f16* __restrict__ xpad, f16* __restrict__ fused)
{
    int tid = blockIdx.x*256 + threadIdx.x;     // NPIX*32 exact
    int pix = tid >> 5, c8 = (tid & 31)*8;
    int b = pix / PIXB; int r = pix - b*PIXB;
    int t = r >> 6, f = r & 63;
    const float* src = x + (size_t)pix*256 + c8;
    f16x8 v;
#pragma unroll
    for (int j = 0; j < 8; ++j) v[j] = (f16)src[j];
    size_t pp = (size_t)(b*TP + t + 1)*FP + (f + 1);
    *(f16x8*)(xpad + pp*256 + c8) = v;
    *(f16x8*)(fused + pp*768 + 512 + c8) = v;
}

// ---------------------------------------------------------------------------
// conv_qkv: implicit GEMM. M = 31872 pixels (128/tile), N = 1536 (128/tile),
// K = 9 taps x 256. 4 waves (2x2), each wave 64x64 via 4x4 16x16x32 frags.
// LDS tiles [128][64] fp16, XOR-chunk-swizzled (chunk ^= row&7) to kill the
// 128B-stride bank conflict; swizzle applied on the per-lane GLOBAL source
// so the LDS destination stays linear (global_load_lds requirement).
// Epilogue scatters into attention-friendly layouts:
//   q_f,k_f: [b][f][tpad=256][c]   v_f: [b][f][c][tpad=256]
//   q_t,k_t: [b][t][f][c]          v_t: [b][t][c][f]
// ---------------------------------------------------------------------------
__global__ __launch_bounds__(256) void conv_qkv(
    const f16* __restrict__ xpad, const f16* __restrict__ wT,
    const float* __restrict__ biasAll,
    f16* __restrict__ qf, f16* __restrict__ kf, f16* __restrict__ vf,
    f16* __restrict__ qt, f16* __restrict__ kt, f16* __restrict__ vt)
{
    __shared__ f16 ldsA[128*64];
    __shared__ f16 ldsB[128*64];
    const int l   = threadIdx.x & 63;
    const int wid = threadIdx.x >> 6;
    const int nt  = blockIdx.x;   // 0..11
    const int mt  = blockIdx.y;   // 0..248
    const int wm = wid >> 1, wn = wid & 1;

    int aBase[4], bBase[4];
#pragma unroll
    for (int i = 0; i < 4; ++i) {
        int row = wid*32 + i*8 + (l >> 3);
        int ch  = (l & 7) ^ (row & 7);           // pre-swizzled source chunk
        int p = mt*128 + row;
        int b = p / PIXB; int r = p - b*PIXB;
        int t = r >> 6, f = r & 63;
        aBase[i] = ((b*TP + t + 1)*FP + (f + 1))*256 + ch*8;
        bBase[i] = (nt*128 + row)*256 + ch*8;
    }

    f32x4 acc[4][4];
#pragma unroll
    for (int mi = 0; mi < 4; ++mi)
#pragma unroll
        for (int ni = 0; ni < 4; ++ni) acc[mi][ni] = {0.f, 0.f, 0.f, 0.f};

    for (int tap = 0; tap < 9; ++tap) {
        const int dt = tap/3 - 1, df = tap%3 - 1;
        const int ash = (dt*FP + df)*256;        // uniform pixel shift
        const f16* wtap = wT + (size_t)tap*1536*256;
        for (int kc = 0; kc < 4; ++kc) {
            const int c0 = kc*64;
#pragma unroll
            for (int i = 0; i < 4; ++i) {
                gl_lds16(xpad + aBase[i] + ash + c0, ldsA + (wid*32 + i*8)*64);
                gl_lds16(wtap + bBase[i] + c0,       ldsB + (wid*32 + i*8)*64);
            }
            __syncthreads();
#pragma unroll
            for (int kk = 0; kk < 2; ++kk) {
                const int cch = kk*4 + (l >> 4);
                f16x8 af[4], bf[4];
#pragma unroll
                for (int mi = 0; mi < 4; ++mi) {
                    int row = wm*64 + mi*16 + (l & 15);
                    af[mi] = *(const f16x8*)(ldsA + row*64 + ((cch ^ (row & 7)) << 3));
                }
#pragma unroll
                for (int ni = 0; ni < 4; ++ni) {
                    int row = wn*64 + ni*16 + (l & 15);
                    bf[ni] = *(const f16x8*)(ldsB + row*64 + ((cch ^ (row & 7)) << 3));
                }
#pragma unroll
                for (int mi = 0; mi < 4; ++mi)
#pragma unroll
                    for (int ni = 0; ni < 4; ++ni)
                        acc[mi][ni] = mfma16(af[mi], bf[ni], acc[mi][ni]);
            }
            __syncthreads();
        }
    }

    const int buf = nt >> 1;   // 0..5 -> qf,kf,vf,qt,kt,vt
    f16* dst = (buf==0)?qf:(buf==1)?kf:(buf==2)?vf:(buf==3)?qt:(buf==4)?kt:vt;
#pragma unroll
    for (int mi = 0; mi < 4; ++mi) {
#pragma unroll
        for (int rg = 0; rg < 4; ++rg) {
            int row = wm*64 + mi*16 + (l >> 4)*4 + rg;   // D: row=(l>>4)*4+reg
            int p = mt*128 + row;
            int b = p / PIXB; int r = p - b*PIXB;
            int t = r >> 6, f = r & 63;
#pragma unroll
            for (int ni = 0; ni < 4; ++ni) {
                int col = wn*64 + ni*16 + (l & 15);      // D: col=l&15
                int ocg = nt*128 + col;
                int ocl = ocg & 255;
                float v = acc[mi][ni][rg] + biasAll[ocg];
                int off;
                if (buf < 2)       off = ((b*64 + f)*LPAD + t)*256 + ocl;
                else if (buf == 2) off = ((b*64 + f)*256 + ocl)*LPAD + t;
                else if (buf < 5)  off = ((b*T_ + t)*64 + f)*256 + ocl;
                else               off = ((b*T_ + t)*256 + ocl)*64 + f;
                dst[off] = (f16)v;
            }
        }
    }
}

// ---------------------------------------------------------------------------
// attn_f: heads (b,f), attention over T (249, padded to 256). One block per
// (head, 64-row q-block); each wave owns 16 q-rows. S kept in registers
// (16 f32x4 = full 256-col row strip), wave-local shfl softmax over 16-lane
// groups, P via wave-private swizzled LDS, PV reads v^T straight from global.
// Epilogue fuses the alpha gate, writes fused[...][0..255].
// ---------------------------------------------------------------------------
__global__ __launch_bounds__(256) void attn_f(
    const f16* __restrict__ qf, const f16* __restrict__ kf, const f16* __restrict__ vf,
    const float* __restrict__ alpha, f16* __restrict__ fused)
{
    __shared__ f16 plds[4][16*256];  // wave-private P strips
    const int l = threadIdx.x & 63;
    const int wid = threadIdx.x >> 6;
    const int head = blockIdx.x >> 2;
    const int qb = blockIdx.x & 3;
    const int b = head >> 6, f = head & 63;
    const f16* qh = qf + (size_t)head*LPAD*256;
    const f16* kh = kf + (size_t)head*LPAD*256;
    const f16* vh = vf + (size_t)head*256*LPAD;
    const int qr0 = qb*64 + wid*16;
    f16* pw = &plds[wid][0];

    f16x8 qa[8];
#pragma unroll
    for (int ks = 0; ks < 8; ++ks)
        qa[ks] = *(const f16x8*)(qh + (qr0 + (l & 15))*256 + ks*32 + (l >> 4)*8);

    f32x4 s[16];
#pragma unroll
    for (int nf = 0; nf < 16; ++nf) s[nf] = {0.f, 0.f, 0.f, 0.f};
#pragma unroll
    for (int ks = 0; ks < 8; ++ks)
#pragma unroll
        for (int nf = 0; nf < 16; ++nf) {
            f16x8 bf = *(const f16x8*)(kh + (nf*16 + (l & 15))*256 + ks*32 + (l >> 4)*8);
            s[nf] = mfma16(qa[ks], bf, s[nf]);
        }

    float inv[4];
#pragma unroll
    for (int rg = 0; rg < 4; ++rg) {
        float m = -1e30f;
#pragma unroll
        for (int nf = 0; nf < 16; ++nf)
            if (nf*16 + (l & 15) < T_) m = fmaxf(m, s[nf][rg]);
#pragma unroll
        for (int d = 1; d < 16; d <<= 1) m = fmaxf(m, __shfl_xor(m, d, 64));
        float sum = 0.f;
#pragma unroll
        for (int nf = 0; nf < 16; ++nf) {
            float p = (nf*16 + (l & 15) < T_) ? __expf(s[nf][rg] - m) : 0.f;
            s[nf][rg] = p;   // unnormalized P; 1/sum folded into epilogue
            sum += p;
        }
#pragma unroll
        for (int d = 1; d < 16; d <<= 1) sum += __shfl_xor(sum, d, 64);
        inv[rg] = 1.f / sum;
    }

#pragma unroll
    for (int nf = 0; nf < 16; ++nf)
#pragma unroll
        for (int rg = 0; rg < 4; ++rg) {
            int row = (l >> 4)*4 + rg;
            int col = nf*16 + (l & 15);
            int byte = (row*512 + col*2) ^ ((row & 7) << 4);
            *(f16*)((char*)pw + byte) = (f16)s[nf][rg];
        }

    f32x4 o[16];
#pragma unroll
    for (int nf = 0; nf < 16; ++nf) o[nf] = {0.f, 0.f, 0.f, 0.f};
#pragma unroll
    for (int ks = 0; ks < 8; ++ks) {
        int row = l & 15;
        int cch = ks*4 + (l >> 4);
        int byte = row*512 + ((cch ^ (row & 7)) << 4);
        f16x8 pa = *(const f16x8*)((const char*)pw + byte);
#pragma unroll
        for (int nf = 0; nf < 16; ++nf) {
            f16x8 bf = *(const f16x8*)(vh + (nf*16 + (l & 15))*LPAD + ks*32 + (l >> 4)*8);
            o[nf] = mfma16(pa, bf, o[nf]);
        }
    }

#pragma unroll
    for (int rg = 0; rg < 4; ++rg) {
        int t = qr0 + (l >> 4)*4 + rg;
        if (t < T_) {
#pragma unroll
            for (int nf = 0; nf < 16; ++nf) {
                int c = nf*16 + (l & 15);
                float v = o[nf][rg] * inv[rg] * alpha[((size_t)(b*T_ + t)*64 + f)*256 + c];
                fused[((size_t)(b*TP + t + 1)*FP + (f + 1))*768 + c] = (f16)v;
            }
        }
    }
}

// ---------------------------------------------------------------------------
// attn_t: heads (b,t), attention over F (64, exact). One block per head.
// ---------------------------------------------------------------------------
__global__ __launch_bounds__(256) void attn_t(
    const f16* __restrict__ qt, const f16* __restrict__ kt, const f16* __restrict__ vt,
    const float* __restrict__ beta, f16* __restrict__ fused)
{
    __shared__ f16 plds[4][16*64];
    const int l = threadIdx.x & 63;
    const int wid = threadIdx.x >> 6;
    const int head = blockIdx.x;        // b*249 + t
    const int b = head / T_, t = head - b*T_;
    const f16* qh = qt + (size_t)head*64*256;
    const f16* kh = kt + (size_t)head*64*256;
    const f16* vh = vt + (size_t)head*256*64;
    const int qr0 = wid*16;
    f16* pw = &plds[wid][0];

    f16x8 qa[8];
#pragma unroll
    for (int ks = 0; ks < 8; ++ks)
        qa[ks] = *(const f16x8*)(qh + (qr0 + (l & 15))*256 + ks*32 + (l >> 4)*8);

    f32x4 s[4];
#pragma unroll
    for (int nf = 0; nf < 4; ++nf) s[nf] = {0.f, 0.f, 0.f, 0.f};
#pragma unroll
    for (int ks = 0; ks < 8; ++ks)
#pragma unroll
        for (int nf = 0; nf < 4; ++nf) {
            f16x8 bf = *(const f16x8*)(kh + (nf*16 + (l & 15))*256 + ks*32 + (l >> 4)*8);
            s[nf] = mfma16(qa[ks], bf, s[nf]);
        }

    float inv[4];
#pragma unroll
    for (int rg = 0; rg < 4; ++rg) {
        float m = -1e30f;
#pragma unroll
        for (int nf = 0; nf < 4; ++nf) m = fmaxf(m, s[nf][rg]);
#pragma unroll
        for (int d = 1; d < 16; d <<= 1) m = fmaxf(m, __shfl_xor(m, d, 64));
        float sum = 0.f;
#pragma unroll
        for (int nf = 0; nf < 4; ++nf) {
            float p = __expf(s[nf][rg] - m);
            s[nf][rg] = p;
            sum += p;
        }
#pragma unroll
        for (int d = 1; d < 16; d <<= 1) sum += __shfl_xor(sum, d, 64);
        inv[rg] = 1.f / sum;
    }

#pragma unroll
    for (int nf = 0; nf < 4; ++nf)
#pragma unroll
        for (int rg = 0; rg < 4; ++rg) {
            int row = (l >> 4)*4 + rg;
            int col = nf*16 + (l & 15);
            int byte = (row*128 + col*2) ^ ((row & 7) << 4);
            *(f16*)((char*)pw + byte) = (f16)s[nf][rg];
        }

    f32x4 o[16];
#pragma unroll
    for (int nf = 0; nf < 16; ++nf) o[nf] = {0.f, 0.f, 0.f, 0.f};
#pragma unroll
    for (int ks = 0; ks < 2; ++ks) {
        int row = l & 15;
        int cch = ks*4 + (l >> 4);
        int byte = row*128 + ((cch ^ (row & 7)) << 4);
        f16x8 pa = *(const f16x8*)((const char*)pw + byte);
#pragma unroll
        for (int nf = 0; nf < 16; ++nf) {
            f16x8 bf = *(const f16x8*)(vh + (nf*16 + (l & 15))*64 + ks*32 + (l >> 4)*8);
            o[nf] = mfma16(pa, bf, o[nf]);
        }
    }

#pragma unroll
    for (int rg = 0; rg < 4; ++rg) {
        int fo = qr0 + (l >> 4)*4 + rg;
#pragma unroll
        for (int nf = 0; nf < 16; ++nf) {
            int c = nf*16 + (l & 15);
            float v = o[nf][rg] * inv[rg] * beta[((size_t)(b*T_ + t)*64 + fo)*256 + c];
            fused[((size_t)(b*TP + t + 1)*FP + (fo + 1))*768 + 256 + c] = (f16)v;
        }
    }
}

// ---------------------------------------------------------------------------
// conv_final: implicit GEMM on fused (padded [B][TP][FP][768]).
// M tile 128 x N 64, K = 9 taps x 768. Wave w owns rows [w*32, w*32+32).
// ---------------------------------------------------------------------------
__global__ __launch_bounds__(256) void conv_final(
    const f16* __restrict__ fused, const f16* __restrict__ wfT,
    const float* __restrict__ biasF, float* __restrict__ out)
{
    __shared__ f16 ldsA[128*64];
    __shared__ f16 ldsB[64*64];
    const int l = threadIdx.x & 63;
    const int wid = threadIdx.x >> 6;
    const int mt = blockIdx.x;  // 0..248

    int aBase[4], bBase[2];
#pragma unroll
    for (int i = 0; i < 4; ++i) {
        int row = wid*32 + i*8 + (l >> 3);
        int ch  = (l & 7) ^ (row & 7);
        int p = mt*128 + row;
        int b = p / PIXB; int r = p - b*PIXB;
        int t = r >> 6, f = r & 63;
        aBase[i] = ((b*TP + t + 1)*FP + (f + 1))*768 + ch*8;
    }
#pragma unroll
    for (int i = 0; i < 2; ++i) {
        int row = wid*16 + i*8 + (l >> 3);
        int ch  = (l & 7) ^ (row & 7);
        bBase[i] = row*768 + ch*8;
    }

    f32x4 acc[2][4];
#pragma unroll
    for (int mi = 0; mi < 2; ++mi)
#pragma unroll
        for (int ni = 0; ni < 4; ++ni) acc[mi][ni] = {0.f, 0.f, 0.f, 0.f};

    for (int tap = 0; tap < 9; ++tap) {
        const int dt = tap/3 - 1, df = tap%3 - 1;
        const int ash = (dt*FP + df)*768;
        const f16* wt = wfT + (size_t)tap*64*768;
        for (int kc = 0; kc < 12; ++kc) {
            const int c0 = kc*64;
#pragma unroll
            for (int i = 0; i < 4; ++i)
                gl_lds16(fused + aBase[i] + ash + c0, ldsA + (wid*32 + i*8)*64);
#pragma unroll
            for (int i = 0; i < 2; ++i)
                gl_lds16(wt + bBase[i] + c0, ldsB + (wid*16 + i*8)*64);
            __syncthreads();
#pragma unroll
            for (int kk = 0; kk < 2; ++kk) {
                const int cch = kk*4 + (l >> 4);
                f16x8 af[2], bf[4];
#pragma unroll
                for (int mi = 0; mi < 2; ++mi) {
                    int row = wid*32 + mi*16 + (l & 15);
                    af[mi] = *(const f16x8*)(ldsA + row*64 + ((cch ^ (row & 7)) << 3));
                }
#pragma unroll
                for (int ni = 0; ni < 4; ++ni) {
                    int row = ni*16 + (l & 15);
                    bf[ni] = *(const f16x8*)(ldsB + row*64 + ((cch ^ (row & 7)) << 3));
                }
#pragma unroll
                for (int mi = 0; mi < 2; ++mi)
#pragma unroll
                    for (int ni = 0; ni < 4; ++ni)
                        acc[mi][ni] = mfma16(af[mi], bf[ni], acc[mi][ni]);
            }
            __syncthreads();
        }
    }

#pragma unroll
    for (int mi = 0; mi < 2; ++mi)
#pragma unroll
        for (int rg = 0; rg < 4; ++rg) {
            int row = wid*32 + mi*16 + (l >> 4)*4 + rg;
            int p = mt*128 + row;
#pragma unroll
            for (int ni = 0; ni < 4; ++ni) {
                int oc = ni*16 + (l & 15);
                out[(size_t)p*64 + oc] = acc[mi][ni][rg] + biasF[oc];
            }
        }
}

// ---------------------------------------------------------------------------
extern "C" void kernel_launch(void* const* d_in, const int* in_sizes, int n_in,
                              void* d_out, int out_size, void* d_ws, size_t ws_size,
                              hipStream_t stream) {
    (void)in_sizes; (void)n_in; (void)out_size;
    const float* x    = (const float*)d_in[0];
    const float* wqf  = (const float*)d_in[1];
    const float* bqf  = (const float*)d_in[2];
    const float* wkf  = (const float*)d_in[3];
    const float* bkf  = (const float*)d_in[4];
    const float* wvf  = (const float*)d_in[5];
    const float* bvf  = (const float*)d_in[6];
    const float* wqt  = (const float*)d_in[7];
    const float* bqt  = (const float*)d_in[8];
    const float* wkt  = (const float*)d_in[9];
    const float* bkt  = (const float*)d_in[10];
    const float* wvt  = (const float*)d_in[11];
    const float* bvt  = (const float*)d_in[12];
    const float* wfin = (const float*)d_in[13];
    const float* bfin = (const float*)d_in[14];
    const float* alpha= (const float*)d_in[15];
    const float* beta = (const float*)d_in[16];

    if (ws_size < WS_NEED) return;   // workspace insufficient -> visible failure

    char* ws = (char*)d_ws;
    f16* fused  = (f16*)(ws + OFF_FUSED);
    f16* xpad   = (f16*)(ws + OFF_XPAD);
    f16* qf     = (f16*)(ws + OFF_QF);
    f16* kf     = (f16*)(ws + OFF_KF);
    f16* vf     = (f16*)(ws + OFF_VF);
    f16* qt     = (f16*)(ws + OFF_QT);
    f16* kt     = (f16*)(ws + OFF_KT);
    f16* vt     = (f16*)(ws + OFF_VT);
    f16* wT     = (f16*)(ws + OFF_WT);
    f16* wfT    = (f16*)(ws + OFF_WFT);
    float* bAll = (float*)(ws + OFF_BALL);
    float* bF   = (float*)(ws + OFF_BF);

    // zero padded borders (and v_f pad columns: 0 * P avoids 0*garbage NaN)
    hipMemsetAsync(fused, 0, FUSED_BYTES, stream);
    hipMemsetAsync(xpad,  0, XPAD_BYTES,  stream);
    hipMemsetAsync(vf,    0, QF_BYTES,    stream);

    prep_w<<<dim3((9*1536*256 + 255)/256), dim3(256), 0, stream>>>(
        wqf, wkf, wvf, wqt, wkt, wvt, wfin,
        bqf, bkf, bvf, bqt, bkt, bvt, bfin, wT, wfT, bAll, bF);
    prep_x<<<dim3(NPIX*32/256), dim3(256), 0, stream>>>(x, xpad, fused);
    conv_qkv<<<dim3(12, 249), dim3(256), 0, stream>>>(xpad, wT, bAll, qf, kf, vf, qt, kt, vt);
    attn_f<<<dim3(512), dim3(256), 0, stream>>>(qf, kf, vf, alpha, fused);
    attn_t<<<dim3(498), dim3(256), 0, stream>>>(qt, kt, vt, beta, fused);
    conv_final<<<dim3(249), dim3(256), 0, stream>>>(fused, wfT, bF, (float*)d_out);
}